// Round 6
// baseline (610.346 us; speedup 1.0000x reference)
//
#include <hip/hip_runtime.h>
#include <math.h>

#define N_NODES 50000
#define N_EDGES 800000
#define E_TOT   (N_EDGES + N_NODES)
#define F_IN    256
#define HEADS   8
#define OUTC    10
#define HID     80
#define NEG_SLOPE 0.2f

// ---------------- CSR build ----------------

__global__ __launch_bounds__(256) void hist_k(const int* __restrict__ ei, int* __restrict__ cnt) {
    int e = blockIdx.x * blockDim.x + threadIdx.x;
    if (e >= E_TOT) return;
    int d = (e < N_EDGES) ? ei[N_EDGES + e] : (e - N_EDGES);
    atomicAdd(&cnt[d], 1);
}

__global__ __launch_bounds__(1024) void scan_k(const int* __restrict__ cnt, int* __restrict__ rowptr) {
    __shared__ int wsum[16];
    __shared__ int carry_s;
    const int tid = threadIdx.x;
    const int lane = tid & 63, wid = tid >> 6;
    if (tid == 0) carry_s = 0;
    __syncthreads();
    for (int base = 0; base < N_NODES; base += 1024) {
        int i = base + tid;
        int v = (i < N_NODES) ? cnt[i] : 0;
        int s = v;
        #pragma unroll
        for (int off = 1; off < 64; off <<= 1) {
            int t = __shfl_up(s, off, 64);
            if (lane >= off) s += t;
        }
        if (lane == 63) wsum[wid] = s;
        int carry = carry_s;
        __syncthreads();
        if (wid == 0 && lane < 16) {
            int w = wsum[lane];
            #pragma unroll
            for (int off = 1; off < 16; off <<= 1) {
                int t = __shfl_up(w, off, 16);
                if (lane >= off) w += t;
            }
            wsum[lane] = w;  // inclusive scan of wave sums
        }
        __syncthreads();
        int woff = (wid > 0) ? wsum[wid - 1] : 0;
        int incl = s + woff;
        int excl = incl - v;
        if (i < N_NODES) rowptr[i] = carry + excl;
        int total = wsum[15];
        __syncthreads();
        if (tid == 0) carry_s = carry + total;
        __syncthreads();
    }
    if (tid == 0) rowptr[N_NODES] = carry_s;
}

__global__ __launch_bounds__(256) void scatter_k(const int* __restrict__ ei,
                                                 const int* __restrict__ rowptr,
                                                 int* __restrict__ cursor,
                                                 int* __restrict__ csr) {
    int e = blockIdx.x * blockDim.x + threadIdx.x;
    if (e >= E_TOT) return;
    int s, d;
    if (e < N_EDGES) { s = ei[e]; d = ei[N_EDGES + e]; }
    else { s = e - N_EDGES; d = s; }
    int pos = rowptr[d] + atomicAdd(&cursor[d], 1);
    csr[pos] = s;
}

// ---------------- tile transpose: x[50000][256] -> xT[256][50000] ----------

__global__ __launch_bounds__(256) void transp_k(const float* __restrict__ in,
                                                float* __restrict__ outT) {
    __shared__ float t[64][65];
    const int tx = threadIdx.x & 63;
    const int ty = threadIdx.x >> 6;       // 0..3
    const int r0 = blockIdx.x * 64;        // node-block
    const int c0 = blockIdx.y * 64;        // feature-block
    #pragma unroll
    for (int i = 0; i < 16; ++i) {
        int r = ty * 16 + i;
        int gr = r0 + r;
        if (gr < N_NODES) t[r][tx] = in[(size_t)gr * F_IN + c0 + tx];
    }
    __syncthreads();
    #pragma unroll
    for (int i = 0; i < 16; ++i) {
        int c = ty * 16 + i;
        int gr = r0 + tx;
        if (gr < N_NODES) outT[(size_t)(c0 + c) * N_NODES + gr] = t[tx][c];
    }
}

// ---------------- dual GEMM from A^T: xl = A@Wl, xr = A@Wr ----------------
// AT: [K][50000]. Lane owns 2 consecutive rows (float2 coalesced loads: 8 cache
// lines/instr, 100% line use). Wave owns 20 cols; blockIdx.y picks Wl or Wr.
// W read wave-uniform -> scalar pipe. 2 rows/thread halves s_load per FMA.

__global__ __launch_bounds__(256) void gemm4_k(const float* __restrict__ AT, int K,
                                               const float* __restrict__ Wl,
                                               const float* __restrict__ Wr,
                                               float* __restrict__ xl,
                                               float* __restrict__ xr) {
    const int lane = threadIdx.x & 63;
    const int wv = __builtin_amdgcn_readfirstlane(threadIdx.x >> 6);
    const int mat = blockIdx.y;              // 0 -> Wl/xl, 1 -> Wr/xr
    const int j0 = wv * 20;
    const int row0 = blockIdx.x * 128;
    const int rbase = row0 + 2 * lane;
    const int rload = (rbase <= N_NODES - 2) ? rbase : (N_NODES - 2);

    const float* __restrict__ W = mat ? Wr : Wl;
    float* __restrict__ Xo = mat ? xr : xl;

    float acc0[20], acc1[20];
    #pragma unroll
    for (int j = 0; j < 20; ++j) { acc0[j] = 0.f; acc1[j] = 0.f; }

    for (int kb = 0; kb < K; kb += 4) {
        float2 a[4];
        #pragma unroll
        for (int t = 0; t < 4; ++t)
            a[t] = *reinterpret_cast<const float2*>(AT + (size_t)(kb + t) * N_NODES + rload);
        #pragma unroll
        for (int t = 0; t < 4; ++t) {
            const float* __restrict__ wrow = W + (size_t)(kb + t) * HID + j0;
            const float ax = a[t].x, ay = a[t].y;
            #pragma unroll
            for (int q = 0; q < 5; ++q) {
                const float4 w = *reinterpret_cast<const float4*>(wrow + q * 4);
                acc0[q * 4 + 0] = fmaf(ax, w.x, acc0[q * 4 + 0]);
                acc0[q * 4 + 1] = fmaf(ax, w.y, acc0[q * 4 + 1]);
                acc0[q * 4 + 2] = fmaf(ax, w.z, acc0[q * 4 + 2]);
                acc0[q * 4 + 3] = fmaf(ax, w.w, acc0[q * 4 + 3]);
                acc1[q * 4 + 0] = fmaf(ay, w.x, acc1[q * 4 + 0]);
                acc1[q * 4 + 1] = fmaf(ay, w.y, acc1[q * 4 + 1]);
                acc1[q * 4 + 2] = fmaf(ay, w.z, acc1[q * 4 + 2]);
                acc1[q * 4 + 3] = fmaf(ay, w.w, acc1[q * 4 + 3]);
            }
        }
    }

    if (rbase < N_NODES) {
        float* op = Xo + (size_t)rbase * HID + j0;
        #pragma unroll
        for (int q = 0; q < 5; ++q)
            *reinterpret_cast<float4*>(op + q * 4) =
                make_float4(acc0[q * 4 + 0], acc0[q * 4 + 1], acc0[q * 4 + 2], acc0[q * 4 + 3]);
    }
    if (rbase + 1 < N_NODES) {
        float* op = Xo + (size_t)(rbase + 1) * HID + j0;
        #pragma unroll
        for (int q = 0; q < 5; ++q)
            *reinterpret_cast<float4*>(op + q * 4) =
                make_float4(acc1[q * 4 + 0], acc1[q * 4 + 1], acc1[q * 4 + 2], acc1[q * 4 + 3]);
    }
}

// ---------------- per-node online-softmax aggregation (lane = head) ----------
// lane&7 = head (lane-local logit), lane>>3 = edge slot (8-way), 3 flash
// merges. Epilogue writes EITHER row-major out (final layer) OR transposed
// outT[c][node] (feeds next layer's gemm4).

__global__ __launch_bounds__(256) void agg2_k(const float* __restrict__ xl,
                                              const float* __restrict__ xr,
                                              const int* __restrict__ rowptr,
                                              const int* __restrict__ csr,
                                              const float* __restrict__ att,
                                              const float* __restrict__ bias,
                                              float* __restrict__ out,
                                              float* __restrict__ outT) {
    const int tid = threadIdx.x;
    const int lane = tid & 63;
    const int node = blockIdx.x * 4 + (tid >> 6);
    if (node >= N_NODES) return;
    const int eg = lane >> 3;   // edge slot 0..7
    const int h = lane & 7;     // head
    const int cb = h * 10;

    float att10[10], xr10[10];
    #pragma unroll
    for (int c = 0; c < 10; ++c) {
        att10[c] = att[cb + c];
        xr10[c] = xr[(size_t)node * HID + cb + c];
    }
    const int ro = rowptr[node];
    const int deg = rowptr[node + 1] - ro;

    float m = -INFINITY, s = 0.f;
    float acc[10];
    #pragma unroll
    for (int c = 0; c < 10; ++c) acc[c] = 0.f;

    for (int i = eg; i < deg; i += 8) {
        const int src = csr[ro + i];
        const float* xlp = xl + (size_t)src * HID + cb;
        float xl10[10];
        float logit = 0.f;
        #pragma unroll
        for (int c = 0; c < 10; ++c) {
            xl10[c] = xlp[c];
            float e = xl10[c] + xr10[c];
            e = (e > 0.f) ? e : NEG_SLOPE * e;
            logit = fmaf(e, att10[c], logit);
        }
        const float nm = fmaxf(m, logit);
        const float scale = __expf(m - nm);      // m=-inf -> 0
        const float p = __expf(logit - nm);
        s = s * scale + p;
        #pragma unroll
        for (int c = 0; c < 10; ++c) acc[c] = acc[c] * scale + p * xl10[c];
        m = nm;
    }

    #pragma unroll
    for (int off = 8; off <= 32; off <<= 1) {
        const float om = __shfl_xor(m, off, 64);
        const float os = __shfl_xor(s, off, 64);
        float oacc[10];
        #pragma unroll
        for (int c = 0; c < 10; ++c) oacc[c] = __shfl_xor(acc[c], off, 64);
        const float nm = fmaxf(m, om);
        const float sc1 = (m == -INFINITY) ? 0.f : __expf(m - nm);
        const float sc2 = (om == -INFINITY) ? 0.f : __expf(om - nm);
        s = s * sc1 + os * sc2;
        #pragma unroll
        for (int c = 0; c < 10; ++c) acc[c] = acc[c] * sc1 + oacc[c] * sc2;
        m = nm;
    }

    if (lane < 8) {
        const float inv = 1.f / (s + 1e-16f);
        #pragma unroll
        for (int c = 0; c < 10; ++c) {
            float v = acc[c] * inv + bias[cb + c];
            v = (v > 0.f) ? v : (__expf(v) - 1.f);   // ELU
            if (outT) outT[(size_t)(cb + c) * N_NODES + node] = v;
            else      out[(size_t)node * HID + cb + c] = v;
        }
    }
}

// ---------------- launch ----------------

extern "C" void kernel_launch(void* const* d_in, const int* in_sizes, int n_in,
                              void* d_out, int out_size, void* d_ws, size_t ws_size,
                              hipStream_t stream) {
    const float* x  = (const float*)d_in[0];
    const int*   ei = (const int*)d_in[1];
    const float* Wl[3]   = {(const float*)d_in[2], (const float*)d_in[6],  (const float*)d_in[10]};
    const float* Wr[3]   = {(const float*)d_in[3], (const float*)d_in[7],  (const float*)d_in[11]};
    const float* attp[3] = {(const float*)d_in[4], (const float*)d_in[8],  (const float*)d_in[12]};
    const float* bp[3]   = {(const float*)d_in[5], (const float*)d_in[9],  (const float*)d_in[13]};

    char* ws = (char*)d_ws;
    size_t off = 0;
    auto alloc = [&](size_t bytes) -> void* {
        void* p = ws + off;
        off += (bytes + 255) & ~(size_t)255;
        return p;
    };
    int* cnt    = (int*)alloc((size_t)N_NODES * 4);
    int* cursor = (int*)alloc((size_t)N_NODES * 4);
    int* rowptr = (int*)alloc((size_t)(N_NODES + 1) * 4);
    int* csr    = (int*)alloc((size_t)E_TOT * 4);
    float* xl   = (float*)alloc((size_t)N_NODES * HID * 4);
    float* xr   = (float*)alloc((size_t)N_NODES * HID * 4);
    float* xT   = (float*)alloc((size_t)F_IN * N_NODES * 4);   // 51.2 MB
    // aliases inside xT's region (sequential stream order makes this safe:
    // gemm4 layer0 finishes reading xT before agg2 layer0 writes actAT)
    float* actAT = xT;                                   // [80][50000]
    float* actBT = xT + (size_t)HID * N_NODES;           // [80][50000]

    hipMemsetAsync(cnt, 0, (size_t)N_NODES * 4, stream);
    hipMemsetAsync(cursor, 0, (size_t)N_NODES * 4, stream);

    hist_k<<<(E_TOT + 255) / 256, 256, 0, stream>>>(ei, cnt);
    scan_k<<<1, 1024, 0, stream>>>(cnt, rowptr);
    scatter_k<<<(E_TOT + 255) / 256, 256, 0, stream>>>(ei, rowptr, cursor, csr);

    transp_k<<<dim3(782, 4), 256, 0, stream>>>(x, xT);

    const float* AT_l[3] = {xT, actAT, actBT};
    float* outT_l[3]     = {actAT, actBT, nullptr};
    for (int l = 0; l < 3; ++l) {
        const int K = (l == 0) ? F_IN : HID;
        gemm4_k<<<dim3((N_NODES + 127) / 128, 2), 256, 0, stream>>>(
            AT_l[l], K, Wl[l], Wr[l], xl, xr);
        float* out_l = (l == 2) ? (float*)d_out : nullptr;
        agg2_k<<<N_NODES / 4, 256, 0, stream>>>(xl, xr, rowptr, csr, attp[l], bp[l],
                                                out_l, outT_l[l]);
    }
}

// Round 7
// 514.585 us; speedup vs baseline: 1.1861x; 1.1861x over previous
//
#include <hip/hip_runtime.h>
#include <math.h>

#define N_NODES 50000
#define N_EDGES 800000
#define E_TOT   (N_EDGES + N_NODES)
#define F_IN    256
#define HEADS   8
#define OUTC    10
#define HID     80
#define NEG_SLOPE 0.2f

// ---------------- CSR build ----------------

__global__ __launch_bounds__(256) void hist_k(const int* __restrict__ ei, int* __restrict__ cnt) {
    int e = blockIdx.x * blockDim.x + threadIdx.x;
    if (e >= E_TOT) return;
    int d = (e < N_EDGES) ? ei[N_EDGES + e] : (e - N_EDGES);
    atomicAdd(&cnt[d], 1);
}

__global__ __launch_bounds__(1024) void scan_k(const int* __restrict__ cnt, int* __restrict__ rowptr) {
    __shared__ int wsum[16];
    __shared__ int carry_s;
    const int tid = threadIdx.x;
    const int lane = tid & 63, wid = tid >> 6;
    if (tid == 0) carry_s = 0;
    __syncthreads();
    for (int base = 0; base < N_NODES; base += 1024) {
        int i = base + tid;
        int v = (i < N_NODES) ? cnt[i] : 0;
        int s = v;
        #pragma unroll
        for (int off = 1; off < 64; off <<= 1) {
            int t = __shfl_up(s, off, 64);
            if (lane >= off) s += t;
        }
        if (lane == 63) wsum[wid] = s;
        int carry = carry_s;
        __syncthreads();
        if (wid == 0 && lane < 16) {
            int w = wsum[lane];
            #pragma unroll
            for (int off = 1; off < 16; off <<= 1) {
                int t = __shfl_up(w, off, 16);
                if (lane >= off) w += t;
            }
            wsum[lane] = w;  // inclusive scan of wave sums
        }
        __syncthreads();
        int woff = (wid > 0) ? wsum[wid - 1] : 0;
        int incl = s + woff;
        int excl = incl - v;
        if (i < N_NODES) rowptr[i] = carry + excl;
        int total = wsum[15];
        __syncthreads();
        if (tid == 0) carry_s = carry + total;
        __syncthreads();
    }
    if (tid == 0) rowptr[N_NODES] = carry_s;
}

__global__ __launch_bounds__(256) void scatter_k(const int* __restrict__ ei,
                                                 const int* __restrict__ rowptr,
                                                 int* __restrict__ cursor,
                                                 int* __restrict__ csr) {
    int e = blockIdx.x * blockDim.x + threadIdx.x;
    if (e >= E_TOT) return;
    int s, d;
    if (e < N_EDGES) { s = ei[e]; d = ei[N_EDGES + e]; }
    else { s = e - N_EDGES; d = s; }
    int pos = rowptr[d] + atomicAdd(&cursor[d], 1);
    csr[pos] = s;
}

// ---------------- LDS-transposed dual GEMM ----------------
// Block = 128 rows x 20 cols/wave. A tile staged coalesced (float4) and stored
// TRANSPOSED in LDS sa[16][128]: lane reads sa[k][lane] -> stride-1 across
// lanes = conflict-free (2 lanes/bank is free). W via wave-uniform s_load.
// 2 rows/lane amortizes W over 40 FMAs/k. blockIdx.y: 0 -> Wl/xl, 1 -> Wr/xr.

__global__ __launch_bounds__(256) void gemm5_k(const float* __restrict__ A, int K,
                                               const float* __restrict__ Wl,
                                               const float* __restrict__ Wr,
                                               float* __restrict__ xl,
                                               float* __restrict__ xr) {
    __shared__ float sa[16][128];
    const int tid = threadIdx.x;
    const int lane = tid & 63;
    const int wv = __builtin_amdgcn_readfirstlane(tid >> 6);  // 0..3
    const int mat = blockIdx.y;           // 0 -> Wl/xl, 1 -> Wr/xr
    const int j0 = wv * 20;               // col base within 80
    const int row0 = blockIdx.x * 128;

    const float* __restrict__ W = mat ? Wr : Wl;
    float* __restrict__ Xo = mat ? xr : xl;

    const int sr = tid >> 2;   // staging row 0..63 (within half)
    const int sq = tid & 3;    // staging float4 chunk 0..3

    float acc0[20], acc1[20];
    #pragma unroll
    for (int j = 0; j < 20; ++j) { acc0[j] = 0.f; acc1[j] = 0.f; }

    for (int kb = 0; kb < K; kb += 16) {
        #pragma unroll
        for (int h = 0; h < 2; ++h) {
            const int gr = row0 + h * 64 + sr;
            const int grc = (gr < N_NODES) ? gr : (N_NODES - 1);
            const float4 v = *reinterpret_cast<const float4*>(
                A + (size_t)grc * K + kb + sq * 4);
            sa[sq * 4 + 0][h * 64 + sr] = v.x;
            sa[sq * 4 + 1][h * 64 + sr] = v.y;
            sa[sq * 4 + 2][h * 64 + sr] = v.z;
            sa[sq * 4 + 3][h * 64 + sr] = v.w;
        }
        __syncthreads();
        #pragma unroll
        for (int k = 0; k < 16; ++k) {
            const float a0 = sa[k][lane];
            const float a1 = sa[k][64 + lane];
            const float* __restrict__ wrow = W + (size_t)(kb + k) * HID + j0;
            #pragma unroll
            for (int q = 0; q < 5; ++q) {
                const float4 w = *reinterpret_cast<const float4*>(wrow + q * 4);
                acc0[q * 4 + 0] = fmaf(a0, w.x, acc0[q * 4 + 0]);
                acc0[q * 4 + 1] = fmaf(a0, w.y, acc0[q * 4 + 1]);
                acc0[q * 4 + 2] = fmaf(a0, w.z, acc0[q * 4 + 2]);
                acc0[q * 4 + 3] = fmaf(a0, w.w, acc0[q * 4 + 3]);
                acc1[q * 4 + 0] = fmaf(a1, w.x, acc1[q * 4 + 0]);
                acc1[q * 4 + 1] = fmaf(a1, w.y, acc1[q * 4 + 1]);
                acc1[q * 4 + 2] = fmaf(a1, w.z, acc1[q * 4 + 2]);
                acc1[q * 4 + 3] = fmaf(a1, w.w, acc1[q * 4 + 3]);
            }
        }
        __syncthreads();
    }

    const int r0 = row0 + lane;
    if (r0 < N_NODES) {
        float* op = Xo + (size_t)r0 * HID + j0;
        #pragma unroll
        for (int q = 0; q < 5; ++q)
            *reinterpret_cast<float4*>(op + q * 4) =
                make_float4(acc0[q * 4 + 0], acc0[q * 4 + 1], acc0[q * 4 + 2], acc0[q * 4 + 3]);
    }
    const int r1 = row0 + 64 + lane;
    if (r1 < N_NODES) {
        float* op = Xo + (size_t)r1 * HID + j0;
        #pragma unroll
        for (int q = 0; q < 5; ++q)
            *reinterpret_cast<float4*>(op + q * 4) =
                make_float4(acc1[q * 4 + 0], acc1[q * 4 + 1], acc1[q * 4 + 2], acc1[q * 4 + 3]);
    }
}

// ---------------- per-node online-softmax aggregation (lane = head) ----------
// lane&7 = head (lane-local logit, zero per-edge shuffles), lane>>3 = edge slot
// (8-way), 3 flash merges at the end. Row-major output (feeds gemm5 staging).

__global__ __launch_bounds__(256) void agg2_k(const float* __restrict__ xl,
                                              const float* __restrict__ xr,
                                              const int* __restrict__ rowptr,
                                              const int* __restrict__ csr,
                                              const float* __restrict__ att,
                                              const float* __restrict__ bias,
                                              float* __restrict__ out) {
    const int tid = threadIdx.x;
    const int lane = tid & 63;
    const int node = blockIdx.x * 4 + (tid >> 6);
    if (node >= N_NODES) return;
    const int eg = lane >> 3;   // edge slot 0..7
    const int h = lane & 7;     // head
    const int cb = h * 10;

    float att10[10], xr10[10];
    #pragma unroll
    for (int c = 0; c < 10; ++c) {
        att10[c] = att[cb + c];
        xr10[c] = xr[(size_t)node * HID + cb + c];
    }
    const int ro = rowptr[node];
    const int deg = rowptr[node + 1] - ro;

    float m = -INFINITY, s = 0.f;
    float acc[10];
    #pragma unroll
    for (int c = 0; c < 10; ++c) acc[c] = 0.f;

    for (int i = eg; i < deg; i += 8) {
        const int src = csr[ro + i];
        const float* xlp = xl + (size_t)src * HID + cb;
        float xl10[10];
        float logit = 0.f;
        #pragma unroll
        for (int c = 0; c < 10; ++c) {
            xl10[c] = xlp[c];
            float e = xl10[c] + xr10[c];
            e = (e > 0.f) ? e : NEG_SLOPE * e;
            logit = fmaf(e, att10[c], logit);
        }
        const float nm = fmaxf(m, logit);
        const float scale = __expf(m - nm);      // m=-inf -> 0
        const float p = __expf(logit - nm);
        s = s * scale + p;
        #pragma unroll
        for (int c = 0; c < 10; ++c) acc[c] = acc[c] * scale + p * xl10[c];
        m = nm;
    }

    #pragma unroll
    for (int off = 8; off <= 32; off <<= 1) {
        const float om = __shfl_xor(m, off, 64);
        const float os = __shfl_xor(s, off, 64);
        float oacc[10];
        #pragma unroll
        for (int c = 0; c < 10; ++c) oacc[c] = __shfl_xor(acc[c], off, 64);
        const float nm = fmaxf(m, om);
        const float sc1 = (m == -INFINITY) ? 0.f : __expf(m - nm);
        const float sc2 = (om == -INFINITY) ? 0.f : __expf(om - nm);
        s = s * sc1 + os * sc2;
        #pragma unroll
        for (int c = 0; c < 10; ++c) acc[c] = acc[c] * sc1 + oacc[c] * sc2;
        m = nm;
    }

    if (lane < 8) {
        const float inv = 1.f / (s + 1e-16f);
        #pragma unroll
        for (int c = 0; c < 10; ++c) {
            float v = acc[c] * inv + bias[cb + c];
            v = (v > 0.f) ? v : (__expf(v) - 1.f);   // ELU
            out[(size_t)node * HID + cb + c] = v;
        }
    }
}

// ---------------- launch ----------------

extern "C" void kernel_launch(void* const* d_in, const int* in_sizes, int n_in,
                              void* d_out, int out_size, void* d_ws, size_t ws_size,
                              hipStream_t stream) {
    const float* x  = (const float*)d_in[0];
    const int*   ei = (const int*)d_in[1];
    const float* Wl[3]   = {(const float*)d_in[2], (const float*)d_in[6],  (const float*)d_in[10]};
    const float* Wr[3]   = {(const float*)d_in[3], (const float*)d_in[7],  (const float*)d_in[11]};
    const float* attp[3] = {(const float*)d_in[4], (const float*)d_in[8],  (const float*)d_in[12]};
    const float* bp[3]   = {(const float*)d_in[5], (const float*)d_in[9],  (const float*)d_in[13]};

    char* ws = (char*)d_ws;
    size_t off = 0;
    auto alloc = [&](size_t bytes) -> void* {
        void* p = ws + off;
        off += (bytes + 255) & ~(size_t)255;
        return p;
    };
    int* cnt    = (int*)alloc((size_t)N_NODES * 4);
    int* cursor = (int*)alloc((size_t)N_NODES * 4);
    int* rowptr = (int*)alloc((size_t)(N_NODES + 1) * 4);
    int* csr    = (int*)alloc((size_t)E_TOT * 4);
    float* xl   = (float*)alloc((size_t)N_NODES * HID * 4);
    float* xr   = (float*)alloc((size_t)N_NODES * HID * 4);
    float* actA = (float*)alloc((size_t)N_NODES * HID * 4);
    float* actB = (float*)alloc((size_t)N_NODES * HID * 4);

    hipMemsetAsync(cnt, 0, (size_t)N_NODES * 4, stream);
    hipMemsetAsync(cursor, 0, (size_t)N_NODES * 4, stream);

    hist_k<<<(E_TOT + 255) / 256, 256, 0, stream>>>(ei, cnt);
    scan_k<<<1, 1024, 0, stream>>>(cnt, rowptr);
    scatter_k<<<(E_TOT + 255) / 256, 256, 0, stream>>>(ei, rowptr, cursor, csr);

    for (int l = 0; l < 3; ++l) {
        const float* act_in = (l == 0) ? x : (l == 1 ? actA : actB);
        const int K = (l == 0) ? F_IN : HID;
        gemm5_k<<<dim3((N_NODES + 127) / 128, 2), 256, 0, stream>>>(
            act_in, K, Wl[l], Wr[l], xl, xr);
        float* out_l = (l == 0) ? actA : (l == 1 ? actB : (float*)d_out);
        agg2_k<<<N_NODES / 4, 256, 0, stream>>>(xl, xr, rowptr, csr, attp[l], bp[l], out_l);
    }
}